// Round 11
// baseline (42433.914 us; speedup 1.0000x reference)
//
#include <hip/hip_runtime.h>

namespace {
constexpr int kB  = 32;
constexpr int kT  = 1024;
constexpr int kD  = 512;
constexpr int kH  = 1024;
constexpr int kLV = 128;
constexpr int kNG = 4 * kH + 2 * kLV;   // 4352
constexpr int kNBLK = 512;              // 2 blocks/CU -> 4 waves/SIMD
constexpr int kNTHR = 512;
constexpr int kCPB  = 17;               // 16 lstm + 1 lvl cols per A-block
// ws float offsets
constexpr int kOffH0 = 16384;           // after 512-flag region
constexpr int kOffWF = kOffH0 + 2 * kB * kH + 2 * kB * kNG;
}

typedef float vfloat4 __attribute__((ext_vector_type(4)));
typedef _Float16 half2_t __attribute__((ext_vector_type(2)));
typedef _Float16 half8_t __attribute__((ext_vector_type(8)));
typedef unsigned short ushort_t;

static __device__ __forceinline__ unsigned ld_flag(const unsigned* p) {
  return __hip_atomic_load(p, __ATOMIC_RELAXED, __HIP_MEMORY_SCOPE_AGENT);
}
static __device__ __forceinline__ void st_flag(unsigned* p, unsigned v) {
  __hip_atomic_store(p, v, __ATOMIC_RELAXED, __HIP_MEMORY_SCOPE_AGENT);
}
static __device__ __forceinline__ float ld_coh(const float* p) {
  return __hip_atomic_load(p, __ATOMIC_RELAXED, __HIP_MEMORY_SCOPE_AGENT);
}
// write-through store to the coherent point (no dirty-L2 state)
static __device__ __forceinline__ void st_wt(float* p, float v) {
  asm volatile("global_store_dword %0, %1, off sc0 sc1" :: "v"(p), "v"(v) : "memory");
}
// 16 coherent 16B loads (two 512-col segments), overlapped, completed INSIDE
// one asm block (no in-flight asm outputs across compiler-visible code).
static __device__ __forceinline__ void ld_sc_x16(vfloat4 v[16],
                                                 const float* b0, const float* b1) {
  asm volatile(
      "global_load_dwordx4 %0,  %16, off sc0 sc1\n\t"
      "global_load_dwordx4 %1,  %16, off offset:16 sc0 sc1\n\t"
      "global_load_dwordx4 %2,  %16, off offset:32 sc0 sc1\n\t"
      "global_load_dwordx4 %3,  %16, off offset:48 sc0 sc1\n\t"
      "global_load_dwordx4 %4,  %16, off offset:64 sc0 sc1\n\t"
      "global_load_dwordx4 %5,  %16, off offset:80 sc0 sc1\n\t"
      "global_load_dwordx4 %6,  %16, off offset:96 sc0 sc1\n\t"
      "global_load_dwordx4 %7,  %16, off offset:112 sc0 sc1\n\t"
      "global_load_dwordx4 %8,  %17, off sc0 sc1\n\t"
      "global_load_dwordx4 %9,  %17, off offset:16 sc0 sc1\n\t"
      "global_load_dwordx4 %10, %17, off offset:32 sc0 sc1\n\t"
      "global_load_dwordx4 %11, %17, off offset:48 sc0 sc1\n\t"
      "global_load_dwordx4 %12, %17, off offset:64 sc0 sc1\n\t"
      "global_load_dwordx4 %13, %17, off offset:80 sc0 sc1\n\t"
      "global_load_dwordx4 %14, %17, off offset:96 sc0 sc1\n\t"
      "global_load_dwordx4 %15, %17, off offset:112 sc0 sc1\n\t"
      "s_waitcnt vmcnt(0)"
      : "=&v"(v[0]), "=&v"(v[1]), "=&v"(v[2]), "=&v"(v[3]),
        "=&v"(v[4]), "=&v"(v[5]), "=&v"(v[6]), "=&v"(v[7]),
        "=&v"(v[8]), "=&v"(v[9]), "=&v"(v[10]), "=&v"(v[11]),
        "=&v"(v[12]), "=&v"(v[13]), "=&v"(v[14]), "=&v"(v[15])
      : "v"(b0), "v"(b1)
      : "memory");
}
static __device__ __forceinline__ float fdot2(unsigned a, unsigned b, float c) {
  return __builtin_amdgcn_fdot2(__builtin_bit_cast(half2_t, a),
                                __builtin_bit_cast(half2_t, b), c, false);
}
static __device__ __forceinline__ unsigned pkrtz(float a, float b) {
  return __builtin_bit_cast(unsigned, __builtin_amdgcn_cvt_pkrtz(a, b));
}

// -------- fp32 -> fp16 weight conversion (one-time pre-pass) --------
__global__ __launch_bounds__(256) void cvt_fp16_kernel(
    const float* __restrict__ src, ushort_t* __restrict__ dst, int n8) {
  int i = blockIdx.x * 256 + threadIdx.x;
  if (i >= n8) return;
  const vfloat4* s4 = (const vfloat4*)src;
  vfloat4 a = s4[2 * i], b = s4[2 * i + 1];
  half8_t o;
  o[0] = (_Float16)a.x; o[1] = (_Float16)a.y;
  o[2] = (_Float16)a.z; o[3] = (_Float16)a.w;
  o[4] = (_Float16)b.x; o[5] = (_Float16)b.y;
  o[6] = (_Float16)b.z; o[7] = (_Float16)b.w;
  ((half8_t*)dst)[i] = o;
}

__global__ __launch_bounds__(kNTHR, 4) void onlstm_kernel(
    const float* __restrict__ x,
    const float* __restrict__ bl0, const float* __restrict__ bv0,
    const float* __restrict__ bl1, const float* __restrict__ bv1,
    const ushort_t* __restrict__ wf0u, const ushort_t* __restrict__ wf1u,
    float* __restrict__ out, float* __restrict__ ws)
{
  const int tid = threadIdx.x;
  const int bid = blockIdx.x;

  // ---- workspace ----
  unsigned* flags = (unsigned*)ws;            // [512] stride-16 uints (32 KB)
  unsigned* genp  = (unsigned*)ws + 8192;
  float* h0     = ws + kOffH0;                // [32][1024]
  float* h1     = h0 + kB * kH;
  float* gates0 = h1 + kB * kH;               // [32][4352]
  float* gates1 = gates0 + kB * kNG;

  // LDS: weights as 16B granules, permuted (p = j*16 + s within each 512-k seg)
  __shared__ uint4 wlds4[kCPB * 256];         // 69,632 B
  __shared__ float gst[kB][20];               // gate-store bounce (pad 20)
  __shared__ float ih_sh[kLV], fh_sh[kLV];
  __shared__ float smx[8];

  unsigned seq = 0;
  // flags-only barrier (proven r8/r9), scaled to 512 blocks
  auto gridbar = [&]() {
    ++seq;
    asm volatile("s_waitcnt vmcnt(0)" ::: "memory");
    __syncthreads();
    if (bid == 0) {
      if (tid >= 1 && tid < kNBLK) {
        while (ld_flag(&flags[tid * 16]) != seq) __builtin_amdgcn_s_sleep(2);
      }
      __syncthreads();
      if (tid == 0) st_flag(genp, seq);
    } else {
      if (tid == 0) {
        st_flag(&flags[bid * 16], seq);
        while (ld_flag(genp) != seq) __builtin_amdgcn_s_sleep(2);
      }
      __syncthreads();
    }
    asm volatile("" ::: "memory");
  };

  // ---- roles ----
  const int role = bid >> 8;                  // 0: layer0, 1: layer1
  const int g    = bid & 255;                 // 256 blocks per role, 17 cols each
  const int K    = role ? 2048 : 1536;
  const int ngr  = K >> 3;                    // 16B granules per col (256/192)
  const float* bl = role ? bl1 : bl0;
  const float* bv = role ? bv1 : bv0;
  float* gates = role ? gates1 : gates0;
  const ushort_t* wf = role ? wf1u : wf0u;

  const int s_  = tid & 15;                   // K-slice within 512-seg (32 floats)
  const int row = tid >> 4;                   // batch row 0..31
  const int pb  = (g & 127) >> 2;             // phase-B row (g<128 only)
  const int qq4 = g & 3;                      // phase-B col quarter

  // ---- one-time: weights global(fp16) -> LDS, granule-permuted ----
  {
    for (int cc = 0; cc < kCPB; ++cc) {
      int jcol = (cc < 16) ? (g * 16 + cc) : (4096 + g);
      const uint4* src = (const uint4*)(wf + (size_t)jcol * K);
      for (int kg = tid; kg < ngr; kg += kNTHR) {
        int si = kg >> 6, kgs = kg & 63;
        int s2 = kgs >> 2, j2 = kgs & 3;
        wlds4[cc * ngr + (si << 6) + (j2 << 4) + s2] = src[kg];
      }
    }
    __syncthreads();
  }

  // zero h0,h1 (write-through)
  {
    int idx = bid * kNTHR + tid;
    if (idx < 2 * kB * kH) st_wt(h0 + idx, 0.f);
  }
  float creg = 0.f;
  gridbar();

  float acc[kCPB];
  uint4 cmb[8];

  // FMA one 512-k segment against cm[0..3] (32 packed halfs)
  auto do_seg = [&](int si, const uint4* cm) {
    const uint4* wp0 = &wlds4[(si << 6) + s_];
#pragma unroll
    for (int cc = 0; cc < kCPB; ++cc) {
      const uint4* wp = wp0 + cc * ngr;
      uint4 w0 = wp[0], w1 = wp[16], w2 = wp[32], w3 = wp[48];
      float a = acc[cc];
      a = fdot2(cm[0].x, w0.x, a); a = fdot2(cm[0].y, w0.y, a);
      a = fdot2(cm[0].z, w0.z, a); a = fdot2(cm[0].w, w0.w, a);
      a = fdot2(cm[1].x, w1.x, a); a = fdot2(cm[1].y, w1.y, a);
      a = fdot2(cm[1].z, w1.z, a); a = fdot2(cm[1].w, w1.w, a);
      a = fdot2(cm[2].x, w2.x, a); a = fdot2(cm[2].y, w2.y, a);
      a = fdot2(cm[2].z, w2.z, a); a = fdot2(cm[2].w, w2.w, a);
      a = fdot2(cm[3].x, w3.x, a); a = fdot2(cm[3].y, w3.y, a);
      a = fdot2(cm[3].z, w3.z, a); a = fdot2(cm[3].w, w3.w, a);
      acc[cc] = a;
    }
  };
  auto pack4 = [&](const vfloat4* v, uint4* cm) {
#pragma unroll
    for (int j = 0; j < 4; ++j) {
      cm[j].x = pkrtz(v[2 * j].x, v[2 * j].y);
      cm[j].y = pkrtz(v[2 * j].z, v[2 * j].w);
      cm[j].z = pkrtz(v[2 * j + 1].x, v[2 * j + 1].y);
      cm[j].w = pkrtz(v[2 * j + 1].z, v[2 * j + 1].w);
    }
  };

  // cell update (phase B), r9-proven distributed mapping
  auto cellB = [&](const float* gbase, float* hb, float& cr, float* outp, int t) {
    const float* gr = gbase + (size_t)pb * kNG;
    const int lane = tid & 63, wv2 = tid >> 6;
    const bool sm = tid < 128;
    const bool cl = tid < 256;

    float vi = 0.f, vf = 0.f, vo = 0.f, vg = 0.f;
    int j = qq4 * 256 + tid;
    if (cl) {                                 // hoisted: latency under softmax
      vi = ld_coh(gr + j);
      vf = ld_coh(gr + kH + j);
      vo = ld_coh(gr + 2 * kH + j);
      vg = ld_coh(gr + 3 * kH + j);
    }
    float ai = 0.f, af = 0.f;
    if (sm) { ai = ld_coh(gr + 4096 + tid); af = ld_coh(gr + 4096 + kLV + tid); }
    float mi = ai, mf = af;
    if (sm) {
#pragma unroll
      for (int d2 = 32; d2 > 0; d2 >>= 1) {
        mi = fmaxf(mi, __shfl_xor(mi, d2));
        mf = fmaxf(mf, __shfl_xor(mf, d2));
      }
      if (lane == 0) { smx[wv2] = mi; smx[2 + wv2] = mf; }
    }
    __syncthreads();
    mi = fmaxf(smx[0], smx[1]);
    mf = fmaxf(smx[2], smx[3]);
    float ei = 0.f, Pi = 0.f, Pf = 0.f;
    if (sm) {
      ei = __expf(ai - mi);
      float ef = __expf(af - mf);
      Pi = ei; Pf = ef;
#pragma unroll
      for (int d2 = 1; d2 < 64; d2 <<= 1) {
        float ni = __shfl_up(Pi, d2);
        float nf = __shfl_up(Pf, d2);
        if (lane >= d2) { Pi += ni; Pf += nf; }
      }
      if (lane == 63) { smx[4 + wv2] = Pi; smx[6 + wv2] = Pf; }
    }
    __syncthreads();
    float Si = smx[4] + smx[5], Sf = smx[6] + smx[7];
    if (sm) {
      if (wv2 == 1) { Pi += smx[4]; Pf += smx[6]; }
      ih_sh[tid] = Pf / Sf;                   // cumsum(softmax(cc_f_h))
      fh_sh[tid] = (Si - Pi + ei) / Si;       // rev-cumsum(softmax(rev cc_i_h))
    }
    __syncthreads();
    if (cl) {
      float i_ = 1.f / (1.f + __expf(-vi));
      float f_ = 1.f / (1.f + __expf(-vf));
      float o_ = 1.f / (1.f + __expf(-vo));
      float g_ = tanhf(vg);
      int l2 = j >> 3;
      float ih = ih_sh[l2], fh = fh_sh[l2];
      float w  = ih * fh;
      float cold = cr;
      float cn = w * (f_ * cold + i_ * g_) + (fh - w) * cold + (ih - w) * g_;
      float hn = o_ * tanhf(cn);
      cr = cn;
      st_wt(hb + (size_t)pb * kH + j, hn);
      if (outp) st_wt(outp + ((size_t)pb * kT + t) * kH + j, hn);
    }
  };

  for (int e = 0; e <= kT; ++e) {
    const bool act = (role == 0) ? (e < kT) : (e >= 1);
    const int t = (role == 0) ? e : e - 1;

    // ========== Phase A: gates = [x_t, h] @ W^T + b ==========
    if (act) {
#pragma unroll
      for (int cc = 0; cc < kCPB; ++cc) acc[cc] = 0.f;
      vfloat4 v[16];
      if (role == 0) {
        // seg 0: x (immutable -> plain cached loads)
        const float* px = x + ((size_t)row * kT + t) * kD + s_ * 32;
#pragma unroll
        for (int i = 0; i < 8; ++i) v[i] = *(const vfloat4*)(px + i * 4);
        pack4(v, cmb); do_seg(0, cmb);
        // segs 1,2: h0 (one batched coherent x16)
        ld_sc_x16(v, h0 + (size_t)row * kH + s_ * 32,
                     h0 + (size_t)row * kH + 512 + s_ * 32);
        pack4(v, cmb); pack4(v + 8, cmb + 4);
        do_seg(1, cmb); do_seg(2, cmb + 4);
      } else {
        // segs 0,1: h0(t) (one x16)
        ld_sc_x16(v, h0 + (size_t)row * kH + s_ * 32,
                     h0 + (size_t)row * kH + 512 + s_ * 32);
        pack4(v, cmb); pack4(v + 8, cmb + 4);
        do_seg(0, cmb); do_seg(1, cmb + 4);
        // segs 2,3: h1 (one x16)
        ld_sc_x16(v, h1 + (size_t)row * kH + s_ * 32,
                     h1 + (size_t)row * kH + 512 + s_ * 32);
        pack4(v, cmb); pack4(v + 8, cmb + 4);
        do_seg(2, cmb); do_seg(3, cmb + 4);
      }
      // in-wave reduce over the 16 K-slices (s = lane bits 0..3)
#pragma unroll
      for (int cc = 0; cc < kCPB; ++cc) {
        float a = acc[cc];
        a += __shfl_xor(a, 1);
        a += __shfl_xor(a, 2);
        a += __shfl_xor(a, 4);
        a += __shfl_xor(a, 8);
        acc[cc] = a;
      }
      // bounce through LDS -> lane-coalesced write-through stores (r9 fix)
      if (s_ == 0) {
#pragma unroll
        for (int cc = 0; cc < kCPB; ++cc) gst[row][cc] = acc[cc];
      }
      __syncthreads();
      for (int o = tid; o < kB * kCPB; o += kNTHR) {
        int r2 = o / kCPB;
        int cc = o - r2 * kCPB;
        int j = (cc < 16) ? (g * 16 + cc) : (4096 + g);
        float bias = (cc < 16) ? bl[g * 16 + cc] : bv[g];
        st_wt(gates + (size_t)r2 * kNG + j, gst[r2][cc] + bias);
      }
    }
    gridbar();

    // ========== Phase B: distributed (r9 mapping), g<128 of each role ==========
    if (g < 128) {
      if (role == 0) {
        if (e < kT) cellB(gates0, h0, creg, nullptr, e);      // layer 0, t=e
      } else {
        if (e >= 1) cellB(gates1, h1, creg, out, e - 1);      // layer 1, t=e-1
      }
    }
    gridbar();
  }
}

extern "C" void kernel_launch(void* const* d_in, const int* in_sizes, int n_in,
                              void* d_out, int out_size, void* d_ws, size_t ws_size,
                              hipStream_t stream) {
  const float* x   = (const float*)d_in[0];
  const float* Wl0 = (const float*)d_in[1];
  const float* bl0 = (const float*)d_in[2];
  const float* Wv0 = (const float*)d_in[3];
  const float* bv0 = (const float*)d_in[4];
  const float* Wl1 = (const float*)d_in[5];
  const float* bl1 = (const float*)d_in[6];
  const float* Wv1 = (const float*)d_in[7];
  const float* bv1 = (const float*)d_in[8];
  (void)in_sizes; (void)n_in; (void)out_size; (void)ws_size;

  float* ws = (float*)d_ws;
  ushort_t* wf0 = (ushort_t*)(ws + kOffWF);                 // [4352][1536] fp16
  ushort_t* wf1 = wf0 + (size_t)4352 * 1536;                // [4352][2048] fp16

  // pre-pass: convert weights to fp16 (Wl then Wv rows, per layer)
  {
    int n;
    n = 4096 * 1536 / 8;
    cvt_fp16_kernel<<<(n + 255) / 256, 256, 0, stream>>>(Wl0, wf0, n);
    n = 256 * 1536 / 8;
    cvt_fp16_kernel<<<(n + 255) / 256, 256, 0, stream>>>(
        Wv0, wf0 + (size_t)4096 * 1536, n);
    n = 4096 * 2048 / 8;
    cvt_fp16_kernel<<<(n + 255) / 256, 256, 0, stream>>>(Wl1, wf1, n);
    n = 256 * 2048 / 8;
    cvt_fp16_kernel<<<(n + 255) / 256, 256, 0, stream>>>(
        Wv1, wf1 + (size_t)4096 * 2048, n);
  }

  onlstm_kernel<<<dim3(kNBLK), dim3(kNTHR), 0, stream>>>(
      x, bl0, bv0, bl1, bv1, wf0, wf1, (float*)d_out, ws);
}

// Round 12
// 39163.153 us; speedup vs baseline: 1.0835x; 1.0835x over previous
//
#include <hip/hip_runtime.h>

namespace {
constexpr int kB  = 32;
constexpr int kT  = 1024;
constexpr int kD  = 512;
constexpr int kH  = 1024;
constexpr int kLV = 128;
constexpr int kNG = 4 * kH + 2 * kLV;   // 4352
constexpr int kNBLK = 256;
constexpr int kNTHR = 512;
// ws float offsets (r9)
constexpr int kOffH0 = 8192;
constexpr int kOffWF = kOffH0 + 2 * kB * kH + 2 * kB * kNG;
// LDS byte offsets
constexpr int kCombOff = 147456;        // max weight-frag region (3 L0 tiles)
constexpr int kRedOff  = kCombOff + 8320;   // comb [32][130] halfs
constexpr int kIhOff   = kRedOff + 4096;    // red 4 tiles x 64 lanes x 16B
constexpr int kFhOff   = kIhOff + 512;
constexpr int kSmxOff  = kFhOff + 512;
constexpr int kLdsBytes = kSmxOff + 32;     // 160,928 <= 163,840
}

typedef float vfloat4 __attribute__((ext_vector_type(4)));
typedef float floatx4 __attribute__((ext_vector_type(4)));
typedef _Float16 half8_t __attribute__((ext_vector_type(8)));
typedef _Float16 halfv8 __attribute__((ext_vector_type(8)));
typedef unsigned short ushort_t;

static __device__ __forceinline__ unsigned ld_flag(const unsigned* p) {
  return __hip_atomic_load(p, __ATOMIC_RELAXED, __HIP_MEMORY_SCOPE_AGENT);
}
static __device__ __forceinline__ void st_flag(unsigned* p, unsigned v) {
  __hip_atomic_store(p, v, __ATOMIC_RELAXED, __HIP_MEMORY_SCOPE_AGENT);
}
static __device__ __forceinline__ float ld_coh(const float* p) {
  return __hip_atomic_load(p, __ATOMIC_RELAXED, __HIP_MEMORY_SCOPE_AGENT);
}
static __device__ __forceinline__ void st_wt(float* p, float v) {
  asm volatile("global_store_dword %0, %1, off sc0 sc1" :: "v"(p), "v"(v) : "memory");
}
// 16 coherent 16B loads completed INSIDE one asm block (proven r10/r11).
static __device__ __forceinline__ void ld_sc_x16(vfloat4 v[16],
                                                 const float* b0, const float* b1) {
  asm volatile(
      "global_load_dwordx4 %0,  %16, off sc0 sc1\n\t"
      "global_load_dwordx4 %1,  %16, off offset:16 sc0 sc1\n\t"
      "global_load_dwordx4 %2,  %16, off offset:32 sc0 sc1\n\t"
      "global_load_dwordx4 %3,  %16, off offset:48 sc0 sc1\n\t"
      "global_load_dwordx4 %4,  %16, off offset:64 sc0 sc1\n\t"
      "global_load_dwordx4 %5,  %16, off offset:80 sc0 sc1\n\t"
      "global_load_dwordx4 %6,  %16, off offset:96 sc0 sc1\n\t"
      "global_load_dwordx4 %7,  %16, off offset:112 sc0 sc1\n\t"
      "global_load_dwordx4 %8,  %17, off sc0 sc1\n\t"
      "global_load_dwordx4 %9,  %17, off offset:16 sc0 sc1\n\t"
      "global_load_dwordx4 %10, %17, off offset:32 sc0 sc1\n\t"
      "global_load_dwordx4 %11, %17, off offset:48 sc0 sc1\n\t"
      "global_load_dwordx4 %12, %17, off offset:64 sc0 sc1\n\t"
      "global_load_dwordx4 %13, %17, off offset:80 sc0 sc1\n\t"
      "global_load_dwordx4 %14, %17, off offset:96 sc0 sc1\n\t"
      "global_load_dwordx4 %15, %17, off offset:112 sc0 sc1\n\t"
      "s_waitcnt vmcnt(0)"
      : "=&v"(v[0]), "=&v"(v[1]), "=&v"(v[2]), "=&v"(v[3]),
        "=&v"(v[4]), "=&v"(v[5]), "=&v"(v[6]), "=&v"(v[7]),
        "=&v"(v[8]), "=&v"(v[9]), "=&v"(v[10]), "=&v"(v[11]),
        "=&v"(v[12]), "=&v"(v[13]), "=&v"(v[14]), "=&v"(v[15])
      : "v"(b0), "v"(b1)
      : "memory");
}
static __device__ __forceinline__ unsigned pkrtz(float a, float b) {
  return __builtin_bit_cast(unsigned, __builtin_amdgcn_cvt_pkrtz(a, b));
}
static __device__ __forceinline__ uint4 pack2(vfloat4 a, vfloat4 b) {
  uint4 r;
  r.x = pkrtz(a.x, a.y); r.y = pkrtz(a.z, a.w);
  r.z = pkrtz(b.x, b.y); r.w = pkrtz(b.z, b.w);
  return r;
}

// -------- fp32 -> fp16 weight conversion (one-time pre-pass) --------
__global__ __launch_bounds__(256) void cvt_fp16_kernel(
    const float* __restrict__ src, ushort_t* __restrict__ dst, int n8) {
  int i = blockIdx.x * 256 + threadIdx.x;
  if (i >= n8) return;
  const vfloat4* s4 = (const vfloat4*)src;
  vfloat4 a = s4[2 * i], b = s4[2 * i + 1];
  halfv8 o;
  o[0] = (_Float16)a.x; o[1] = (_Float16)a.y;
  o[2] = (_Float16)a.z; o[3] = (_Float16)a.w;
  o[4] = (_Float16)b.x; o[5] = (_Float16)b.y;
  o[6] = (_Float16)b.z; o[7] = (_Float16)b.w;
  ((halfv8*)dst)[i] = o;
}

__global__ __launch_bounds__(kNTHR, 2) void onlstm_kernel(
    const float* __restrict__ x,
    const float* __restrict__ bl0, const float* __restrict__ bv0,
    const float* __restrict__ bl1, const float* __restrict__ bv1,
    const ushort_t* __restrict__ wf0u, const ushort_t* __restrict__ wf1u,
    float* __restrict__ out, float* __restrict__ ws)
{
  const int tid = threadIdx.x;
  const int bid = blockIdx.x;

  // ---- workspace (r9) ----
  unsigned* flags = (unsigned*)ws;
  unsigned* genp  = (unsigned*)ws + 4096;
  float* h0     = ws + kOffH0;
  float* h1     = h0 + kB * kH;
  float* gates0 = h1 + kB * kH;
  float* gates1 = gates0 + kB * kNG;

  __shared__ __align__(16) char sb[kLdsBytes];
  uint4* wb4   = (uint4*)sb;                    // weight B-fragments
  char*  combp = sb + kCombOff;                 // comb chunk [32][130] halfs
  float* redp  = (float*)(sb + kRedOff);        // stripe reduce
  float* ih_sh = (float*)(sb + kIhOff);
  float* fh_sh = (float*)(sb + kFhOff);
  float* smx   = (float*)(sb + kSmxOff);

  unsigned seq = 0;
  auto gridbar = [&]() {                        // r8/r9-proven flags-only barrier
    ++seq;
    asm volatile("s_waitcnt vmcnt(0)" ::: "memory");
    __syncthreads();
    if (bid == 0) {
      if (tid >= 1 && tid < kNBLK) {
        while (ld_flag(&flags[tid * 16]) != seq) __builtin_amdgcn_s_sleep(2);
      }
      __syncthreads();
      if (tid == 0) st_flag(genp, seq);
    } else {
      if (tid == 0) {
        st_flag(&flags[bid * 16], seq);
        while (ld_flag(genp) != seq) __builtin_amdgcn_s_sleep(2);
      }
      __syncthreads();
    }
    asm volatile("" ::: "memory");
  };

  // ---- A-phase block type ----
  int L, ntile, cb0;
  if (bid < 32)       { L = 0; ntile = 3; cb0 = bid * 48; }
  else if (bid < 120) { L = 0; ntile = 2; cb0 = 1536 + (bid - 32) * 32; }
  else                { L = 1; ntile = 2; cb0 = (bid - 120) * 32; }
  const int K  = L ? 2048 : 1536;
  const int nq = K >> 7;                        // 128-half chunks: 12 or 16
  const int nt = 2 * ntile;
  const ushort_t* wf = L ? wf1u : wf0u;
  const float* blp = L ? bl1 : bl0;
  const float* bvp = L ? bv1 : bv0;
  float* gatesL = L ? gates1 : gates0;

  const int lane = tid & 63;
  const int wv   = tid >> 6;
  const int it   = wv % nt;                     // (tile, rt) index
  const int str  = wv / nt;                     // k-stripe
  const int nstr = (it < 8 - nt) ? 2 : 1;
  const int t2   = it >> 1, rt = it & 1;
  const int tile_off = t2 * (K * 2);            // granules per tile = K/32*64
  const int arow = rt * 16 + (lane & 15);
  const int hw   = lane >> 4;
  const int colg = cb0 + t2 * 16 + (lane & 15);

  const int row = tid & 31;                     // staging: batch row
  const int u   = tid >> 5;                     // staging: k-column group

  // ---- one-time: build weight B-fragments in LDS (lane-linear) ----
  for (int tt = 0; tt < ntile; ++tt) {
    const int colb = cb0 + tt * 16;
    const int ng2 = K * 2;
    for (int idx = tid; idx < ng2; idx += kNTHR) {
      int m = idx >> 6, l2 = idx & 63;
      size_t off = (size_t)(colb + (l2 & 15)) * K + m * 32 + 8 * (l2 >> 4);
      wb4[tt * ng2 + idx] = *(const uint4*)(wf + off);
    }
  }
  float bias_w = 0.f;
  if (str == 0) bias_w = (colg < 4096) ? blp[colg] : bvp[colg - 4096];
  __syncthreads();

  // zero h0,h1
  { int idx = bid * kNTHR + tid; if (idx < 2 * kB * kH) st_wt(h0 + idx, 0.f); }
  float creg = 0.f;
  gridbar();

  // phase-B cell update (r9-proven)
  const int pbB  = (bid & 127) >> 2;
  const int qq4B = bid & 3;
  auto cellB = [&](const float* gbase, float* hb, float& cr, float* outp, int t) {
    const float* gr = gbase + (size_t)pbB * kNG;
    const int wl = tid & 63, wv2 = tid >> 6;
    const bool sm = tid < 128;
    const bool cl = tid < 256;
    float vi = 0.f, vf = 0.f, vo = 0.f, vg = 0.f;
    int j = qq4B * 256 + tid;
    if (cl) {
      vi = ld_coh(gr + j);
      vf = ld_coh(gr + kH + j);
      vo = ld_coh(gr + 2 * kH + j);
      vg = ld_coh(gr + 3 * kH + j);
    }
    float ai = 0.f, af = 0.f;
    if (sm) { ai = ld_coh(gr + 4096 + tid); af = ld_coh(gr + 4096 + kLV + tid); }
    float mi = ai, mf = af;
    if (sm) {
#pragma unroll
      for (int d2 = 32; d2 > 0; d2 >>= 1) {
        mi = fmaxf(mi, __shfl_xor(mi, d2));
        mf = fmaxf(mf, __shfl_xor(mf, d2));
      }
      if (wl == 0) { smx[wv2] = mi; smx[2 + wv2] = mf; }
    }
    __syncthreads();
    mi = fmaxf(smx[0], smx[1]);
    mf = fmaxf(smx[2], smx[3]);
    float ei = 0.f, Pi = 0.f, Pf = 0.f;
    if (sm) {
      ei = __expf(ai - mi);
      float ef = __expf(af - mf);
      Pi = ei; Pf = ef;
#pragma unroll
      for (int d2 = 1; d2 < 64; d2 <<= 1) {
        float ni = __shfl_up(Pi, d2);
        float nf = __shfl_up(Pf, d2);
        if (wl >= d2) { Pi += ni; Pf += nf; }
      }
      if (wl == 63) { smx[4 + wv2] = Pi; smx[6 + wv2] = Pf; }
    }
    __syncthreads();
    float Si = smx[4] + smx[5], Sf = smx[6] + smx[7];
    if (sm) {
      if (wv2 == 1) { Pi += smx[4]; Pf += smx[6]; }
      ih_sh[tid] = Pf / Sf;
      fh_sh[tid] = (Si - Pi + ei) / Si;
    }
    __syncthreads();
    if (cl) {
      float i_ = 1.f / (1.f + __expf(-vi));
      float f_ = 1.f / (1.f + __expf(-vf));
      float o_ = 1.f / (1.f + __expf(-vo));
      float g_ = tanhf(vg);
      int l2 = j >> 3;
      float ih = ih_sh[l2], fh = fh_sh[l2];
      float w  = ih * fh;
      float cold = cr;
      float cn = w * (f_ * cold + i_ * g_) + (fh - w) * cold + (ih - w) * g_;
      float hn = o_ * tanhf(cn);
      cr = cn;
      st_wt(hb + (size_t)pbB * kH + j, hn);
      if (outp) st_wt(outp + ((size_t)pbB * kT + t) * kH + j, hn);
    }
  };

  char* crow = combp + row * 260;

  for (int e = 0; e <= kT; ++e) {
    const bool actA = L ? (e >= 1) : (e < kT);

    // ========== Phase A: gates = [comb] @ W^T + b via MFMA ==========
    if (actA) {
      uint4 PX[4], PH0[8], PH1[8];
      vfloat4 v[16];
      if (L == 0) {
        const float* xp = x + ((size_t)row * kT + e) * kD + u * 32;
#pragma unroll
        for (int i = 0; i < 8; ++i) v[i] = *(const vfloat4*)(xp + i * 4);
#pragma unroll
        for (int j = 0; j < 4; ++j) PX[j] = pack2(v[2 * j], v[2 * j + 1]);
        ld_sc_x16(v, h0 + (size_t)row * kH + u * 64,
                     h0 + (size_t)row * kH + u * 64 + 32);
#pragma unroll
        for (int j = 0; j < 8; ++j) PH0[j] = pack2(v[2 * j], v[2 * j + 1]);
      } else {
        ld_sc_x16(v, h0 + (size_t)row * kH + u * 64,
                     h0 + (size_t)row * kH + u * 64 + 32);
#pragma unroll
        for (int j = 0; j < 8; ++j) PH0[j] = pack2(v[2 * j], v[2 * j + 1]);
        ld_sc_x16(v, h1 + (size_t)row * kH + u * 64,
                     h1 + (size_t)row * kH + u * 64 + 32);
#pragma unroll
        for (int j = 0; j < 8; ++j) PH1[j] = pack2(v[2 * j], v[2 * j + 1]);
      }

      floatx4 acc = {0.f, 0.f, 0.f, 0.f};
      for (int q = 0; q < nq; ++q) {
        __syncthreads();                        // previous chunk consumed
        if (L == 0) {
          if (q < 4) {
            if ((u >> 2) == q) {
#pragma unroll
              for (int j = 0; j < 4; ++j)
                *(uint4*)(crow + ((u & 3) * 32 + j * 8) * 2) = PX[j];
            }
          } else if ((u >> 1) == q - 4) {
#pragma unroll
            for (int j = 0; j < 8; ++j)
              *(uint4*)(crow + ((u & 1) * 64 + j * 8) * 2) = PH0[j];
          }
        } else {
          if (q < 8) {
            if ((u >> 1) == q) {
#pragma unroll
              for (int j = 0; j < 8; ++j)
                *(uint4*)(crow + ((u & 1) * 64 + j * 8) * 2) = PH0[j];
            }
          } else if ((u >> 1) == q - 8) {
#pragma unroll
            for (int j = 0; j < 8; ++j)
              *(uint4*)(crow + ((u & 1) * 64 + j * 8) * 2) = PH1[j];
          }
        }
        __syncthreads();                        // chunk ready
#pragma unroll
        for (int mm = 0; mm < 4; ++mm) {
          int m = q * 4 + mm;
          if ((m & (nstr - 1)) != str) continue;
          uint4 av = *(const uint4*)(combp + arow * 260 + (mm * 32 + 8 * hw) * 2);
          uint4 bw = wb4[tile_off + m * 64 + lane];
          acc = __builtin_amdgcn_mfma_f32_16x16x32_f16(
              __builtin_bit_cast(half8_t, av),
              __builtin_bit_cast(half8_t, bw), acc, 0, 0, 0);
        }
      }
      // stripe reduce + write gates (coalesced per 16-lane quarter)
      if (str == 1) *(floatx4*)(redp + (it * 64 + lane) * 4) = acc;
      __syncthreads();
      if (str == 0) {
        if (nstr == 2) {
          floatx4 o2 = *(const floatx4*)(redp + (it * 64 + lane) * 4);
          acc += o2;
        }
        const int rbase = rt * 16 + hw * 4;
#pragma unroll
        for (int r = 0; r < 4; ++r)
          st_wt(gatesL + (size_t)(rbase + r) * kNG + colg, acc[r] + bias_w);
      }
    }
    gridbar();

    // ========== Phase B (r9 mapping) ==========
    if (bid < 128) {
      if (e < kT) cellB(gates0, h0, creg, nullptr, e);
    } else {
      if (e >= 1) cellB(gates1, h1, creg, out, e - 1);
    }
    gridbar();
  }
}

extern "C" void kernel_launch(void* const* d_in, const int* in_sizes, int n_in,
                              void* d_out, int out_size, void* d_ws, size_t ws_size,
                              hipStream_t stream) {
  const float* x   = (const float*)d_in[0];
  const float* Wl0 = (const float*)d_in[1];
  const float* bl0 = (const float*)d_in[2];
  const float* Wv0 = (const float*)d_in[3];
  const float* bv0 = (const float*)d_in[4];
  const float* Wl1 = (const float*)d_in[5];
  const float* bl1 = (const float*)d_in[6];
  const float* Wv1 = (const float*)d_in[7];
  const float* bv1 = (const float*)d_in[8];
  (void)in_sizes; (void)n_in; (void)out_size; (void)ws_size;

  float* ws = (float*)d_ws;
  ushort_t* wf0 = (ushort_t*)(ws + kOffWF);                 // [4352][1536] fp16
  ushort_t* wf1 = wf0 + (size_t)4352 * 1536;                // [4352][2048] fp16

  {
    int n;
    n = 4096 * 1536 / 8;
    cvt_fp16_kernel<<<(n + 255) / 256, 256, 0, stream>>>(Wl0, wf0, n);
    n = 256 * 1536 / 8;
    cvt_fp16_kernel<<<(n + 255) / 256, 256, 0, stream>>>(
        Wv0, wf0 + (size_t)4096 * 1536, n);
    n = 4096 * 2048 / 8;
    cvt_fp16_kernel<<<(n + 255) / 256, 256, 0, stream>>>(Wl1, wf1, n);
    n = 256 * 2048 / 8;
    cvt_fp16_kernel<<<(n + 255) / 256, 256, 0, stream>>>(
        Wv1, wf1 + (size_t)4096 * 2048, n);
  }

  onlstm_kernel<<<dim3(kNBLK), dim3(kNTHR), 0, stream>>>(
      x, bl0, bv0, bl1, bv1, wf0, wf1, (float*)d_out, ws);
}

// Round 13
// 14239.037 us; speedup vs baseline: 2.9801x; 2.7504x over previous
//
#include <hip/hip_runtime.h>

namespace {
constexpr int kB  = 32;
constexpr int kT  = 1024;
constexpr int kD  = 512;
constexpr int kH  = 1024;
constexpr int kLV = 128;
constexpr int kNG = 4 * kH + 2 * kLV;   // 4352
constexpr int kNBLK = 256;
constexpr int kNTHR = 512;
// ws float offsets (r9)
constexpr int kOffH0 = 8192;
constexpr int kOffWF = kOffH0 + 2 * kB * kH + 2 * kB * kNG;
// LDS byte offsets
constexpr int kRedOff = 3 * 1536 * 2 * 16;   // weight region max: 147456 B
constexpr int kIhOff  = kRedOff + 6144;      // red: 2rt x 3u x 64 lanes x 16B
constexpr int kFhOff  = kIhOff + 512;
constexpr int kSmxOff = kFhOff + 512;
constexpr int kLdsBytes = kSmxOff + 32;      // 154,656 <= 163,840
}

typedef float vfloat4 __attribute__((ext_vector_type(4)));
typedef float floatx4 __attribute__((ext_vector_type(4)));
typedef _Float16 half8_t __attribute__((ext_vector_type(8)));
typedef unsigned short ushort_t;

static __device__ __forceinline__ unsigned ld_flag(const unsigned* p) {
  return __hip_atomic_load(p, __ATOMIC_RELAXED, __HIP_MEMORY_SCOPE_AGENT);
}
static __device__ __forceinline__ void st_flag(unsigned* p, unsigned v) {
  __hip_atomic_store(p, v, __ATOMIC_RELAXED, __HIP_MEMORY_SCOPE_AGENT);
}
static __device__ __forceinline__ float ld_coh(const float* p) {
  return __hip_atomic_load(p, __ATOMIC_RELAXED, __HIP_MEMORY_SCOPE_AGENT);
}
static __device__ __forceinline__ void st_wt(float* p, float v) {
  asm volatile("global_store_dword %0, %1, off sc0 sc1" :: "v"(p), "v"(v) : "memory");
}
// 16 coherent 16B loads: 8 MFMA A-frag m-steps at stride 512B from one base.
// All completed INSIDE one asm block (proven pattern r5-r12).
static __device__ __forceinline__ void ld16h(vfloat4 v[16], const float* b) {
  asm volatile(
      "global_load_dwordx4 %0,  %16, off sc0 sc1\n\t"
      "global_load_dwordx4 %1,  %16, off offset:16 sc0 sc1\n\t"
      "global_load_dwordx4 %2,  %16, off offset:512 sc0 sc1\n\t"
      "global_load_dwordx4 %3,  %16, off offset:528 sc0 sc1\n\t"
      "global_load_dwordx4 %4,  %16, off offset:1024 sc0 sc1\n\t"
      "global_load_dwordx4 %5,  %16, off offset:1040 sc0 sc1\n\t"
      "global_load_dwordx4 %6,  %16, off offset:1536 sc0 sc1\n\t"
      "global_load_dwordx4 %7,  %16, off offset:1552 sc0 sc1\n\t"
      "global_load_dwordx4 %8,  %16, off offset:2048 sc0 sc1\n\t"
      "global_load_dwordx4 %9,  %16, off offset:2064 sc0 sc1\n\t"
      "global_load_dwordx4 %10, %16, off offset:2560 sc0 sc1\n\t"
      "global_load_dwordx4 %11, %16, off offset:2576 sc0 sc1\n\t"
      "global_load_dwordx4 %12, %16, off offset:3072 sc0 sc1\n\t"
      "global_load_dwordx4 %13, %16, off offset:3088 sc0 sc1\n\t"
      "global_load_dwordx4 %14, %16, off offset:3584 sc0 sc1\n\t"
      "global_load_dwordx4 %15, %16, off offset:3600 sc0 sc1\n\t"
      "s_waitcnt vmcnt(0)"
      : "=&v"(v[0]), "=&v"(v[1]), "=&v"(v[2]), "=&v"(v[3]),
        "=&v"(v[4]), "=&v"(v[5]), "=&v"(v[6]), "=&v"(v[7]),
        "=&v"(v[8]), "=&v"(v[9]), "=&v"(v[10]), "=&v"(v[11]),
        "=&v"(v[12]), "=&v"(v[13]), "=&v"(v[14]), "=&v"(v[15])
      : "v"(b)
      : "memory");
}
static __device__ __forceinline__ unsigned pkrtz(float a, float b) {
  return __builtin_bit_cast(unsigned, __builtin_amdgcn_cvt_pkrtz(a, b));
}
static __device__ __forceinline__ uint4 pack2(vfloat4 a, vfloat4 b) {
  uint4 r;
  r.x = pkrtz(a.x, a.y); r.y = pkrtz(a.z, a.w);
  r.z = pkrtz(b.x, b.y); r.w = pkrtz(b.z, b.w);
  return r;
}
static __device__ __forceinline__ floatx4 mfma16(uint4 a, uint4 b, floatx4 c) {
  return __builtin_amdgcn_mfma_f32_16x16x32_f16(
      __builtin_bit_cast(half8_t, a), __builtin_bit_cast(half8_t, b), c, 0, 0, 0);
}

// -------- fp32 -> fp16 weight conversion (one-time pre-pass) --------
__global__ __launch_bounds__(256) void cvt_fp16_kernel(
    const float* __restrict__ src, ushort_t* __restrict__ dst, int n8) {
  int i = blockIdx.x * 256 + threadIdx.x;
  if (i >= n8) return;
  const vfloat4* s4 = (const vfloat4*)src;
  vfloat4 a = s4[2 * i], b = s4[2 * i + 1];
  typedef _Float16 h8 __attribute__((ext_vector_type(8)));
  h8 o;
  o[0] = (_Float16)a.x; o[1] = (_Float16)a.y;
  o[2] = (_Float16)a.z; o[3] = (_Float16)a.w;
  o[4] = (_Float16)b.x; o[5] = (_Float16)b.y;
  o[6] = (_Float16)b.z; o[7] = (_Float16)b.w;
  ((h8*)dst)[i] = o;
}

__global__ __launch_bounds__(kNTHR, 2) void onlstm_kernel(
    const float* __restrict__ x,
    const float* __restrict__ bl0, const float* __restrict__ bv0,
    const float* __restrict__ bl1, const float* __restrict__ bv1,
    const ushort_t* __restrict__ wf0u, const ushort_t* __restrict__ wf1u,
    float* __restrict__ out, float* __restrict__ ws)
{
  const int tid = threadIdx.x;
  const int bid = blockIdx.x;

  // ---- workspace (r9) ----
  unsigned* flags = (unsigned*)ws;
  unsigned* genp  = (unsigned*)ws + 4096;
  float* h0     = ws + kOffH0;
  float* h1     = h0 + kB * kH;
  float* gates0 = h1 + kB * kH;
  float* gates1 = gates0 + kB * kNG;

  __shared__ __align__(16) char sb[kLdsBytes];
  uint4* wb4   = (uint4*)sb;                    // weight B-fragments
  float* redp  = (float*)(sb + kRedOff);        // K-stripe reduce
  float* ih_sh = (float*)(sb + kIhOff);
  float* fh_sh = (float*)(sb + kFhOff);
  float* smx   = (float*)(sb + kSmxOff);

  unsigned seq = 0;
  auto gridbar = [&]() {                        // r8/r9-proven flags-only barrier
    ++seq;
    asm volatile("s_waitcnt vmcnt(0)" ::: "memory");
    __syncthreads();
    if (bid == 0) {
      if (tid >= 1 && tid < kNBLK) {
        while (ld_flag(&flags[tid * 16]) != seq) __builtin_amdgcn_s_sleep(2);
      }
      __syncthreads();
      if (tid == 0) st_flag(genp, seq);
    } else {
      if (tid == 0) {
        st_flag(&flags[bid * 16], seq);
        while (ld_flag(genp) != seq) __builtin_amdgcn_s_sleep(2);
      }
      __syncthreads();
    }
    asm volatile("" ::: "memory");
  };

  // ---- A-phase block type ----
  int L, ntile, cb0;
  if (bid < 32)       { L = 0; ntile = 3; cb0 = bid * 48; }
  else if (bid < 120) { L = 0; ntile = 2; cb0 = 1536 + (bid - 32) * 32; }
  else                { L = 1; ntile = 2; cb0 = (bid - 120) * 32; }
  const int K   = L ? 2048 : 1536;
  const int ts4 = K * 2;                        // uint4 per weight tile
  const bool three = (ntile == 3);
  const ushort_t* wf = L ? wf1u : wf0u;
  const float* blp = L ? bl1 : bl0;
  const float* bvp = L ? bv1 : bv0;
  float* gatesL = L ? gates1 : gates0;

  // wave mapping: rt = row-half, str = K-quarter
  const int lane = tid & 63;
  const int rt   = (tid >> 6) & 1;
  const int str  = tid >> 7;
  const int r_   = rt * 16 + (lane & 15);       // batch row (A-frag row)
  const int koct = lane >> 4;                   // k-octet within 32-k window
  const int colg0 = cb0 + (lane & 15);
  const int colg1 = cb0 + 16 + (lane & 15);
  const int colg2 = cb0 + 32 + (lane & 15);

  // ---- one-time: build weight B-fragments in LDS (lane-linear; r12-proven) ----
  for (int tt = 0; tt < ntile; ++tt) {
    const int colb = cb0 + tt * 16;
    for (int idx = tid; idx < ts4; idx += kNTHR) {
      int m = idx >> 6, l2 = idx & 63;
      size_t off = (size_t)(colb + (l2 & 15)) * K + m * 32 + 8 * (l2 >> 4);
      wb4[tt * ts4 + idx] = *(const uint4*)(wf + off);
    }
  }
  const float b0w = (colg0 < 4096) ? blp[colg0] : bvp[colg0 - 4096];
  const float b1w = (colg1 < 4096) ? blp[colg1] : bvp[colg1 - 4096];
  const float b2w = three ? ((colg2 < 4096) ? blp[colg2] : bvp[colg2 - 4096]) : 0.f;
  __syncthreads();

  // zero h0,h1
  { int idx = bid * kNTHR + tid; if (idx < 2 * kB * kH) st_wt(h0 + idx, 0.f); }
  float creg = 0.f;
  gridbar();

  // phase-B cell update (r9-proven)
  const int pbB  = (bid & 127) >> 2;
  const int qq4B = bid & 3;
  auto cellB = [&](const float* gbase, float* hb, float& cr, float* outp, int t) {
    const float* gr = gbase + (size_t)pbB * kNG;
    const int wl = tid & 63, wv2 = tid >> 6;
    const bool sm = tid < 128;
    const bool cl = tid < 256;
    float vi = 0.f, vf = 0.f, vo = 0.f, vg = 0.f;
    int j = qq4B * 256 + tid;
    if (cl) {
      vi = ld_coh(gr + j);
      vf = ld_coh(gr + kH + j);
      vo = ld_coh(gr + 2 * kH + j);
      vg = ld_coh(gr + 3 * kH + j);
    }
    float ai = 0.f, af = 0.f;
    if (sm) { ai = ld_coh(gr + 4096 + tid); af = ld_coh(gr + 4096 + kLV + tid); }
    float mi = ai, mf = af;
    if (sm) {
#pragma unroll
      for (int d2 = 32; d2 > 0; d2 >>= 1) {
        mi = fmaxf(mi, __shfl_xor(mi, d2));
        mf = fmaxf(mf, __shfl_xor(mf, d2));
      }
      if (wl == 0) { smx[wv2] = mi; smx[2 + wv2] = mf; }
    }
    __syncthreads();
    mi = fmaxf(smx[0], smx[1]);
    mf = fmaxf(smx[2], smx[3]);
    float ei = 0.f, Pi = 0.f, Pf = 0.f;
    if (sm) {
      ei = __expf(ai - mi);
      float ef = __expf(af - mf);
      Pi = ei; Pf = ef;
#pragma unroll
      for (int d2 = 1; d2 < 64; d2 <<= 1) {
        float ni = __shfl_up(Pi, d2);
        float nf = __shfl_up(Pf, d2);
        if (wl >= d2) { Pi += ni; Pf += nf; }
      }
      if (wl == 63) { smx[4 + wv2] = Pi; smx[6 + wv2] = Pf; }
    }
    __syncthreads();
    float Si = smx[4] + smx[5], Sf = smx[6] + smx[7];
    if (sm) {
      if (wv2 == 1) { Pi += smx[4]; Pf += smx[6]; }
      ih_sh[tid] = Pf / Sf;
      fh_sh[tid] = (Si - Pi + ei) / Si;
    }
    __syncthreads();
    if (cl) {
      float i_ = 1.f / (1.f + __expf(-vi));
      float f_ = 1.f / (1.f + __expf(-vf));
      float o_ = 1.f / (1.f + __expf(-vo));
      float g_ = tanhf(vg);
      int l2 = j >> 3;
      float ih = ih_sh[l2], fh = fh_sh[l2];
      float w  = ih * fh;
      float cold = cr;
      float cn = w * (f_ * cold + i_ * g_) + (fh - w) * cold + (ih - w) * g_;
      float hn = o_ * tanhf(cn);
      cr = cn;
      st_wt(hb + (size_t)pbB * kH + j, hn);
      if (outp) st_wt(outp + ((size_t)pbB * kT + t) * kH + j, hn);
    }
  };

  for (int e = 0; e <= kT; ++e) {
    const bool actA = L ? (e >= 1) : (e < kT);

    // ========== Phase A: MFMA, zero syncs in K loop ==========
    if (actA) {
      floatx4 a0 = {0.f,0.f,0.f,0.f}, a1 = a0, a2 = a0;
      uint4 pa[8];
      if (L == 0) {
        // x segment: m-steps str+4j, j=0..3 (plain cached loads; x immutable)
        {
          const float* bx = x + ((size_t)r_ * kT + e) * kD + str * 32 + koct * 8;
          vfloat4 vx[8];
#pragma unroll
          for (int j = 0; j < 4; ++j) {
            vx[2*j]   = *(const vfloat4*)(bx + j * 128);
            vx[2*j+1] = *(const vfloat4*)(bx + j * 128 + 4);
          }
#pragma unroll
          for (int j = 0; j < 4; ++j) pa[j] = pack2(vx[2*j], vx[2*j+1]);
#pragma unroll
          for (int j = 0; j < 4; ++j) {
            const int m = str + 4 * j;
            a0 = mfma16(pa[j], wb4[m * 64 + lane], a0);
            a1 = mfma16(pa[j], wb4[ts4 + m * 64 + lane], a1);
            if (three) a2 = mfma16(pa[j], wb4[2 * ts4 + m * 64 + lane], a2);
          }
        }
        // h0 segment: m-steps 16+str+4j, j=0..7 (coherent batch)
        {
          vfloat4 v[16];
          ld16h(v, h0 + (size_t)r_ * kH + str * 32 + koct * 8);
#pragma unroll
          for (int j = 0; j < 8; ++j) pa[j] = pack2(v[2*j], v[2*j+1]);
#pragma unroll
          for (int j = 0; j < 8; ++j) {
            const int m = 16 + str + 4 * j;
            a0 = mfma16(pa[j], wb4[m * 64 + lane], a0);
            a1 = mfma16(pa[j], wb4[ts4 + m * 64 + lane], a1);
            if (three) a2 = mfma16(pa[j], wb4[2 * ts4 + m * 64 + lane], a2);
          }
        }
      } else {
        // h0 segment: m = str+4j, j=0..7
        {
          vfloat4 v[16];
          ld16h(v, h0 + (size_t)r_ * kH + str * 32 + koct * 8);
#pragma unroll
          for (int j = 0; j < 8; ++j) pa[j] = pack2(v[2*j], v[2*j+1]);
#pragma unroll
          for (int j = 0; j < 8; ++j) {
            const int m = str + 4 * j;
            a0 = mfma16(pa[j], wb4[m * 64 + lane], a0);
            a1 = mfma16(pa[j], wb4[ts4 + m * 64 + lane], a1);
          }
        }
        // h1 segment: m = 32+str+4j, j=0..7
        {
          vfloat4 v[16];
          ld16h(v, h1 + (size_t)r_ * kH + str * 32 + koct * 8);
#pragma unroll
          for (int j = 0; j < 8; ++j) pa[j] = pack2(v[2*j], v[2*j+1]);
#pragma unroll
          for (int j = 0; j < 8; ++j) {
            const int m = 32 + str + 4 * j;
            a0 = mfma16(pa[j], wb4[m * 64 + lane], a0);
            a1 = mfma16(pa[j], wb4[ts4 + m * 64 + lane], a1);
          }
        }
      }
      // cross-wave K-stripe reduce: 3 sequential rounds through 6 KB LDS
      for (int s2 = 1; s2 < 4; ++s2) {
        if (str == s2) {
          *(floatx4*)&redp[((rt * 3 + 0) * 64 + lane) * 4] = a0;
          *(floatx4*)&redp[((rt * 3 + 1) * 64 + lane) * 4] = a1;
          if (three) *(floatx4*)&redp[((rt * 3 + 2) * 64 + lane) * 4] = a2;
        }
        __syncthreads();
        if (str == 0) {
          a0 += *(const floatx4*)&redp[((rt * 3 + 0) * 64 + lane) * 4];
          a1 += *(const floatx4*)&redp[((rt * 3 + 1) * 64 + lane) * 4];
          if (three) a2 += *(const floatx4*)&redp[((rt * 3 + 2) * 64 + lane) * 4];
        }
        __syncthreads();
      }
      // gate write: str0 waves, coalesced 16-lane col groups (r12-proven C map)
      if (str == 0) {
        const int rb = rt * 16 + koct * 4;
#pragma unroll
        for (int r = 0; r < 4; ++r)
          st_wt(gatesL + (size_t)(rb + r) * kNG + colg0, a0[r] + b0w);
#pragma unroll
        for (int r = 0; r < 4; ++r)
          st_wt(gatesL + (size_t)(rb + r) * kNG + colg1, a1[r] + b1w);
        if (three) {
#pragma unroll
          for (int r = 0; r < 4; ++r)
            st_wt(gatesL + (size_t)(rb + r) * kNG + colg2, a2[r] + b2w);
        }
      }
    }
    gridbar();

    // ========== Phase B (r9 mapping) ==========
    if (bid < 128) {
      if (e < kT) cellB(gates0, h0, creg, nullptr, e);
    } else {
      if (e >= 1) cellB(gates1, h1, creg, out, e - 1);
    }
    gridbar();
  }
}

extern "C" void kernel_launch(void* const* d_in, const int* in_sizes, int n_in,
                              void* d_out, int out_size, void* d_ws, size_t ws_size,
                              hipStream_t stream) {
  const float* x   = (const float*)d_in[0];
  const float* Wl0 = (const float*)d_in[1];
  const float* bl0 = (const float*)d_in[2];
  const float* Wv0 = (const float*)d_in[3];
  const float* bv0 = (const float*)d_in[4];
  const float* Wl1 = (const float*)d_in[5];
  const float* bl1 = (const float*)d_in[6];
  const float* Wv1 = (const float*)d_in[7];
  const float* bv1 = (const float*)d_in[8];
  (void)in_sizes; (void)n_in; (void)out_size; (void)ws_size;

  float* ws = (float*)d_ws;
  ushort_t* wf0 = (ushort_t*)(ws + kOffWF);                 // [4352][1536] fp16
  ushort_t* wf1 = wf0 + (size_t)4352 * 1536;                // [4352][2048] fp16

  {
    int n;
    n = 4096 * 1536 / 8;
    cvt_fp16_kernel<<<(n + 255) / 256, 256, 0, stream>>>(Wl0, wf0, n);
    n = 256 * 1536 / 8;
    cvt_fp16_kernel<<<(n + 255) / 256, 256, 0, stream>>>(
        Wv0, wf0 + (size_t)4096 * 1536, n);
    n = 4096 * 2048 / 8;
    cvt_fp16_kernel<<<(n + 255) / 256, 256, 0, stream>>>(Wl1, wf1, n);
    n = 256 * 2048 / 8;
    cvt_fp16_kernel<<<(n + 255) / 256, 256, 0, stream>>>(
        Wv1, wf1 + (size_t)4096 * 2048, n);
  }

  onlstm_kernel<<<dim3(kNBLK), dim3(kNTHR), 0, stream>>>(
      x, bl0, bv0, bl1, bv1, wf0, wf1, (float*)d_out, ws);
}